// Round 2
// baseline (141.602 us; speedup 1.0000x reference)
//
#include <hip/hip_runtime.h>

typedef float  f32x4  __attribute__((ext_vector_type(4)));
typedef short  short8 __attribute__((ext_vector_type(8)));
typedef __bf16 bf16x8 __attribute__((ext_vector_type(8)));

#define DEV static __device__ __forceinline__

DEV f32x4 mfma16(short8 a, short8 b, f32x4 c) {
  return __builtin_amdgcn_mfma_f32_16x16x32_bf16(
      __builtin_bit_cast(bf16x8, a), __builtin_bit_cast(bf16x8, b), c, 0, 0, 0);
}

// split f32 into bf16 hi (truncated) + bf16 lo (RNE of residual): hi+lo ~ f to ~2^-15 rel
DEV void splitf(float f, unsigned short& hi, unsigned short& lo) {
  unsigned u = __builtin_bit_cast(unsigned, f);
  hi = (unsigned short)(u >> 16);
  float hf = __builtin_bit_cast(float, u & 0xFFFF0000u);
  float r = f - hf;
  unsigned v = __builtin_bit_cast(unsigned, r);
  lo = (unsigned short)((v + 0x7FFFu + ((v >> 16) & 1u)) >> 16);
}

#define DDIM 640
#define KCH  20            // 640 / 32 k-chunks for GEMM1
#define MKP_ELEMS (KCH*2*4*64*8)   // 81920 ushorts = 163840 B
#define MVP_OFF   MKP_ELEMS

// Pack Mk (fragment order for GEMM1 B) and Mv^T (fragment order for GEMM2 B) as bf16 hi/lo.
// MkP layout: [c(20)][plane(2)][g(4)][lane(64)][j(8)]  ushort
//   holds Mk[m=16g+(l&15)][d=32c+8*(l>>4)+j]
// MvP layout: [n(40)][c(2)][plane(2)][lane(64)][j(8)]  ushort
//   holds Mv[m=32c+8*(l>>4)+j][d=16n+(l&15)]
__global__ void ea_pack(const float* __restrict__ Mk, const float* __restrict__ Mv,
                        unsigned short* __restrict__ ws) {
  int tid = blockIdx.x * 256 + threadIdx.x;
  unsigned short* MkP = ws;
  unsigned short* MvP = ws + MVP_OFF;
  if (tid < 5120) {                       // 20*4*64 slots
    int c = tid >> 8;
    int g = (tid >> 6) & 3;
    int l = tid & 63;
    int t = l & 15, q = l >> 4;
    const float* src = Mk + (16*g + t) * DDIM + 32*c + 8*q;
    unsigned short* dh = MkP + (((c*2 + 0)*4 + g)*64 + l)*8;
    unsigned short* dl = MkP + (((c*2 + 1)*4 + g)*64 + l)*8;
#pragma unroll
    for (int j = 0; j < 8; ++j) splitf(src[j], dh[j], dl[j]);
  } else if (tid < 10240) {               // 40*2*64 slots
    int s = tid - 5120;
    int n = s >> 7;
    int c = (s >> 6) & 1;
    int l = s & 63;
    int t = l & 15, q = l >> 4;
    const float* src = Mv + (32*c + 8*q) * DDIM + 16*n + t;
    unsigned short* dh = MvP + (((n*2 + c)*2 + 0)*64 + l)*8;
    unsigned short* dl = MvP + (((n*2 + c)*2 + 1)*64 + l)*8;
#pragma unroll
    for (int j = 0; j < 8; ++j) splitf(src[j*DDIM], dh[j], dl[j]);
  }
}

// One block = 32 rows, 4 waves, grid 2048 (= 8 blocks/CU -> up to 32 waves/CU).
// GEMM1: wave w -> row-group a=w&1 (16 rows), m-half p=w>>1 (32 m). Raw scores
// go through LDS (padded) for the cross-wave softmax: 8 threads/row, shfl_xor
// reduce, then W -> LDS bf16 hi/lo with the (granule ^ row&7) XOR swizzle.
// GEMM2: wave w -> n-groups [10w,10w+10), both row-groups.
__global__ __launch_bounds__(256, 8) void ea_main(const float* __restrict__ x,
                                                  const unsigned short* __restrict__ MkP,
                                                  const unsigned short* __restrict__ MvP,
                                                  float* __restrict__ out) {
  __shared__ float Sld[32][68];           // +4 pad: bank-spread + keeps f32x4 alignment
  __shared__ unsigned short Wh[32][64];
  __shared__ unsigned short Wl[32][64];
  const int tid = threadIdx.x;
  const int w = tid >> 6;
  const int l = tid & 63;
  const int t = l & 15;
  const int q = l >> 4;
  const long r0 = (long)blockIdx.x * 32;
  const int a = w & 1;                    // row-group (rows 16a..16a+15)
  const int p = w >> 1;                   // m-half (m 32p..32p+31)

  // ---------------- GEMM1: scores ----------------
  const float* xp = x + (r0 + 16*a + t) * DDIM + 8*q;
  f32x4 acc[2];
  acc[0] = (f32x4){0.f, 0.f, 0.f, 0.f};
  acc[1] = (f32x4){0.f, 0.f, 0.f, 0.f};

#pragma unroll 2
  for (int c = 0; c < KCH; ++c) {
    f32x4 xa = *(const f32x4*)(xp + 32*c);
    f32x4 xb = *(const f32x4*)(xp + 32*c + 4);
    union { short8 s; unsigned short u[8]; } ah, al;
#pragma unroll
    for (int i = 0; i < 4; ++i) {
      splitf(xa[i], ah.u[i],     al.u[i]);
      splitf(xb[i], ah.u[4 + i], al.u[4 + i]);
    }
    const unsigned short* mkc = MkP + c * 4096;
    short8 bh[2], bl[2];
#pragma unroll
    for (int i = 0; i < 2; ++i) {
      int g = 2*p + i;
      bh[i] = *(const short8*)(mkc +        (g*64 + l)*8);
      bl[i] = *(const short8*)(mkc + 2048 + (g*64 + l)*8);
    }
#pragma unroll
    for (int i = 0; i < 2; ++i) {
      acc[i] = mfma16(ah.s, bh[i], acc[i]);
      acc[i] = mfma16(al.s, bh[i], acc[i]);
      acc[i] = mfma16(ah.s, bl[i], acc[i]);
    }
  }

  // scatter raw scores: lane holds S[row=16a+4q+j][m=16*(2p+i)+t]
#pragma unroll
  for (int i = 0; i < 2; ++i) {
#pragma unroll
    for (int j = 0; j < 4; ++j)
      Sld[16*a + 4*q + j][16*(2*p + i) + t] = acc[i][j];
  }
  __syncthreads();

  // ---------------- softmax: 8 threads per row ----------------
  {
    const int row = tid >> 3;
    const int s   = tid & 7;
    f32x4 va = *(const f32x4*)&Sld[row][s*8];
    f32x4 vb = *(const f32x4*)&Sld[row][s*8 + 4];
    float mx = fmaxf(fmaxf(fmaxf(va[0], va[1]), fmaxf(va[2], va[3])),
                     fmaxf(fmaxf(vb[0], vb[1]), fmaxf(vb[2], vb[3])));
#pragma unroll
    for (int mk = 1; mk <= 4; mk <<= 1) mx = fmaxf(mx, __shfl_xor(mx, mk, 64));
    float pv[8], sum = 0.f;
#pragma unroll
    for (int j = 0; j < 4; ++j) { pv[j]   = exp2f((va[j] - mx) * 1.44269504f); sum += pv[j]; }
#pragma unroll
    for (int j = 0; j < 4; ++j) { pv[4+j] = exp2f((vb[j] - mx) * 1.44269504f); sum += pv[4+j]; }
#pragma unroll
    for (int mk = 1; mk <= 4; mk <<= 1) sum += __shfl_xor(sum, mk, 64);
    float inv = 1.0f / sum;
    union { short8 s8; unsigned short u[8]; } wh, wl;
#pragma unroll
    for (int j = 0; j < 8; ++j) splitf(pv[j] * inv, wh.u[j], wl.u[j]);
    const int gr = (s ^ (row & 7)) * 8;    // 8-ushort granule XOR swizzle
    *(short8*)&Wh[row][gr] = wh.s8;
    *(short8*)&Wl[row][gr] = wl.s8;
  }
  __syncthreads();

  // ---------------- GEMM2: out = W @ Mv ----------------
  const int n0 = w * 10;
#pragma unroll 1
  for (int n = n0; n < n0 + 10; ++n) {
    const unsigned short* mvp = MvP + n * 2048;
    short8 vh[2], vl[2];
#pragma unroll
    for (int c = 0; c < 2; ++c) {
      vh[c] = *(const short8*)(mvp + ((c*2 + 0)*64 + l)*8);
      vl[c] = *(const short8*)(mvp + ((c*2 + 1)*64 + l)*8);
    }
#pragma unroll
    for (int rg = 0; rg < 2; ++rg) {
      f32x4 o = (f32x4){0.f, 0.f, 0.f, 0.f};
      const int arow = 16*rg + t;
      const int sw   = (arow & 7) << 3;
#pragma unroll
      for (int c = 0; c < 2; ++c) {
        const int ms = (32*c + 8*q) ^ sw;
        short8 aH = *(const short8*)&Wh[arow][ms];
        short8 aL = *(const short8*)&Wl[arow][ms];
        o = mfma16(aH, vh[c], o);
        o = mfma16(aL, vh[c], o);
        o = mfma16(aH, vl[c], o);
      }
      float* op = out + (r0 + 16*rg + 4*q) * DDIM + 16*n + t;
#pragma unroll
      for (int j = 0; j < 4; ++j) op[j * DDIM] = o[j];
    }
  }
}

extern "C" void kernel_launch(void* const* d_in, const int* in_sizes, int n_in,
                              void* d_out, int out_size, void* d_ws, size_t ws_size,
                              hipStream_t stream) {
  const float* x  = (const float*)d_in[0];
  const float* Mk = (const float*)d_in[1];
  const float* Mv = (const float*)d_in[2];
  float* outp = (float*)d_out;
  unsigned short* ws = (unsigned short*)d_ws;

  ea_pack<<<40, 256, 0, stream>>>(Mk, Mv, ws);
  ea_main<<<2048, 256, 0, stream>>>(x, ws, ws + MVP_OFF, outp);
}

// Round 4
// 121.202 us; speedup vs baseline: 1.1683x; 1.1683x over previous
//
#include <hip/hip_runtime.h>

typedef float  f32x4  __attribute__((ext_vector_type(4)));
typedef short  short8 __attribute__((ext_vector_type(8)));
typedef __bf16 bf16x8 __attribute__((ext_vector_type(8)));

#define DEV static __device__ __forceinline__

DEV f32x4 mfma16(short8 a, short8 b, f32x4 c) {
  return __builtin_amdgcn_mfma_f32_16x16x32_bf16(
      __builtin_bit_cast(bf16x8, a), __builtin_bit_cast(bf16x8, b), c, 0, 0, 0);
}

// split f32 into bf16 hi (truncated) + bf16 lo (RNE of residual): hi+lo ~ f to ~2^-15 rel
DEV void splitf(float f, unsigned short& hi, unsigned short& lo) {
  unsigned u = __builtin_bit_cast(unsigned, f);
  hi = (unsigned short)(u >> 16);
  float hf = __builtin_bit_cast(float, u & 0xFFFF0000u);
  float r = f - hf;
  unsigned v = __builtin_bit_cast(unsigned, r);
  lo = (unsigned short)((v + 0x7FFFu + ((v >> 16) & 1u)) >> 16);
}

#define DDIM 640
#define KCH  20            // 640 / 32 k-chunks for GEMM1
#define MKP_ELEMS (KCH*2*4*64*8)   // 81920 ushorts = 163840 B
#define MVP_OFF   MKP_ELEMS

// Pack Mk (fragment order for GEMM1 B) and Mv^T (fragment order for GEMM2 B) as bf16 hi/lo.
// MkP layout: [c(20)][plane(2)][g(4)][lane(64)][j(8)]  ushort
//   holds Mk[m=16g+(l&15)][d=32c+8*(l>>4)+j]
// MvP layout: [n(40)][c(2)][plane(2)][lane(64)][j(8)]  ushort
//   holds Mv[m=32c+8*(l>>4)+j][d=16n+(l&15)]
__global__ void ea_pack(const float* __restrict__ Mk, const float* __restrict__ Mv,
                        unsigned short* __restrict__ ws) {
  int tid = blockIdx.x * 256 + threadIdx.x;
  unsigned short* MkP = ws;
  unsigned short* MvP = ws + MVP_OFF;
  if (tid < 5120) {                       // 20*4*64 slots
    int c = tid >> 8;
    int g = (tid >> 6) & 3;
    int l = tid & 63;
    int t = l & 15, q = l >> 4;
    const float* src = Mk + (16*g + t) * DDIM + 32*c + 8*q;
    unsigned short* dh = MkP + (((c*2 + 0)*4 + g)*64 + l)*8;
    unsigned short* dl = MkP + (((c*2 + 1)*4 + g)*64 + l)*8;
#pragma unroll
    for (int j = 0; j < 8; ++j) splitf(src[j], dh[j], dl[j]);
  } else if (tid < 10240) {               // 40*2*64 slots
    int s = tid - 5120;
    int n = s >> 7;
    int c = (s >> 6) & 1;
    int l = s & 63;
    int t = l & 15, q = l >> 4;
    const float* src = Mv + (32*c + 8*q) * DDIM + 16*n + t;
    unsigned short* dh = MvP + (((n*2 + c)*2 + 0)*64 + l)*8;
    unsigned short* dl = MvP + (((n*2 + c)*2 + 1)*64 + l)*8;
#pragma unroll
    for (int j = 0; j < 8; ++j) splitf(src[j*DDIM], dh[j], dl[j]);
  }
}

// Fully per-wave: each wave owns 16 rows end-to-end. No __syncthreads anywhere.
// GEMM1 with 3-deep x prefetch (4 slots, distance 3 -> no slot collision) ->
// in-register softmax -> W into a private LDS slab (XOR-swizzled,
// lgkmcnt-waited) -> hoisted A-frags -> GEMM2 over 40 n with double-buffered
// Mv fragments.
__global__ __launch_bounds__(256, 4) void ea_main(const float* __restrict__ x,
                                                  const unsigned short* __restrict__ MkP,
                                                  const unsigned short* __restrict__ MvP,
                                                  float* __restrict__ out) {
  __shared__ __align__(16) unsigned short Wh[4][16][64];
  __shared__ __align__(16) unsigned short Wl[4][16][64];
  const int tid = threadIdx.x;
  const int w = tid >> 6;
  const int l = tid & 63;
  const int t = l & 15;
  const int q = l >> 4;
  const long row0 = (long)blockIdx.x * 64 + 16*w;   // this wave's first row

  // ---------------- GEMM1: scores, 3-deep x prefetch ----------------
  const float* xp = x + (row0 + t) * DDIM + 8*q;
  f32x4 acc[4];
#pragma unroll
  for (int g = 0; g < 4; ++g) acc[g] = (f32x4){0.f, 0.f, 0.f, 0.f};

  f32x4 xbuf[4][2];
#pragma unroll
  for (int c = 0; c < 3; ++c) {
    xbuf[c][0] = *(const f32x4*)(xp + 32*c);
    xbuf[c][1] = *(const f32x4*)(xp + 32*c + 4);
  }
#pragma unroll
  for (int c = 0; c < KCH; ++c) {
    if (c + 3 < KCH) {                      // prefetch 3 chunks ahead: slot (c+3)&3 != c&3
      xbuf[(c+3)&3][0] = *(const f32x4*)(xp + 32*(c+3));
      xbuf[(c+3)&3][1] = *(const f32x4*)(xp + 32*(c+3) + 4);
    }
    union { short8 s; unsigned short u[8]; } ah, al;
#pragma unroll
    for (int i = 0; i < 4; ++i) {
      splitf(xbuf[c&3][0][i], ah.u[i],     al.u[i]);
      splitf(xbuf[c&3][1][i], ah.u[4 + i], al.u[4 + i]);
    }
    const unsigned short* mkc = MkP + c * 4096;
    short8 bh[4], bl[4];
#pragma unroll
    for (int g = 0; g < 4; ++g) {
      bh[g] = *(const short8*)(mkc +        (g*64 + l)*8);
      bl[g] = *(const short8*)(mkc + 2048 + (g*64 + l)*8);
    }
#pragma unroll
    for (int g = 0; g < 4; ++g) {
      acc[g] = mfma16(ah.s, bh[g], acc[g]);
      acc[g] = mfma16(al.s, bh[g], acc[g]);
      acc[g] = mfma16(ah.s, bl[g], acc[g]);
    }
  }

  // ---------------- softmax (in-register, per wave) ----------------
  // lane holds S[row = 4q+j (wave-local)][m = 16g+t]
  float rmax[4], rsum[4];
#pragma unroll
  for (int j = 0; j < 4; ++j)
    rmax[j] = fmaxf(fmaxf(acc[0][j], acc[1][j]), fmaxf(acc[2][j], acc[3][j]));
#pragma unroll
  for (int mk = 1; mk <= 8; mk <<= 1) {
#pragma unroll
    for (int j = 0; j < 4; ++j)
      rmax[j] = fmaxf(rmax[j], __shfl_xor(rmax[j], mk, 64));
  }
  float p[4][4];
#pragma unroll
  for (int g = 0; g < 4; ++g) {
#pragma unroll
    for (int j = 0; j < 4; ++j)
      p[g][j] = exp2f((acc[g][j] - rmax[j]) * 1.44269504f);
  }
#pragma unroll
  for (int j = 0; j < 4; ++j)
    rsum[j] = (p[0][j] + p[1][j]) + (p[2][j] + p[3][j]);
#pragma unroll
  for (int mk = 1; mk <= 8; mk <<= 1) {
#pragma unroll
    for (int j = 0; j < 4; ++j)
      rsum[j] += __shfl_xor(rsum[j], mk, 64);
  }
  float rinv[4];
#pragma unroll
  for (int j = 0; j < 4; ++j) rinv[j] = 1.0f / rsum[j];

  // W -> private LDS slab, XOR swizzle (proven 0-conflict)
#pragma unroll
  for (int g = 0; g < 4; ++g) {
#pragma unroll
    for (int j = 0; j < 4; ++j) {
      float wt = p[g][j] * rinv[j];
      unsigned short hi, lo;
      splitf(wt, hi, lo);
      int row = 4*q + j;
      int ms  = (16*g + t) ^ ((row & 7) << 3);
      Wh[w][row][ms] = hi;
      Wl[w][row][ms] = lo;
    }
  }
  // same-wave cross-lane LDS handoff: wait for all ds_writes to land
  asm volatile("s_waitcnt lgkmcnt(0)" ::: "memory");
  __builtin_amdgcn_sched_barrier(0);

  // hoisted GEMM2 A-fragments: A[row=t][k=32c+8q+j]  (loop-invariant over n)
  short8 aH[2], aL[2];
#pragma unroll
  for (int c = 0; c < 2; ++c) {
    const int ms = (32*c + 8*q) ^ ((t & 7) << 3);
    aH[c] = *(const short8*)&Wh[w][t][ms];
    aL[c] = *(const short8*)&Wl[w][t][ms];
  }

  // ---------------- GEMM2: out = W @ Mv, double-buffered Mv frags ----------------
  short8 vh[2][2], vl[2][2];
#pragma unroll
  for (int c = 0; c < 2; ++c) {
    const unsigned short* mvp = MvP;      // n = 0
    vh[0][c] = *(const short8*)(mvp + ((c*2 + 0)*64 + l)*8);
    vl[0][c] = *(const short8*)(mvp + ((c*2 + 1)*64 + l)*8);
  }
  float* opb = out + (row0 + 4*q) * DDIM + t;
#pragma unroll
  for (int n = 0; n < 40; ++n) {
    const int cur = n & 1, nxt = cur ^ 1;
    if (n + 1 < 40) {
      const unsigned short* mvp = MvP + (n + 1) * 2048;
#pragma unroll
      for (int c = 0; c < 2; ++c) {
        vh[nxt][c] = *(const short8*)(mvp + ((c*2 + 0)*64 + l)*8);
        vl[nxt][c] = *(const short8*)(mvp + ((c*2 + 1)*64 + l)*8);
      }
    }
    f32x4 o = (f32x4){0.f, 0.f, 0.f, 0.f};
#pragma unroll
    for (int c = 0; c < 2; ++c) {
      o = mfma16(aH[c], vh[cur][c], o);
      o = mfma16(aL[c], vh[cur][c], o);
      o = mfma16(aH[c], vl[cur][c], o);
    }
    float* op = opb + 16*n;
#pragma unroll
    for (int j = 0; j < 4; ++j) op[j * DDIM] = o[j];
  }
}

extern "C" void kernel_launch(void* const* d_in, const int* in_sizes, int n_in,
                              void* d_out, int out_size, void* d_ws, size_t ws_size,
                              hipStream_t stream) {
  const float* x  = (const float*)d_in[0];
  const float* Mk = (const float*)d_in[1];
  const float* Mv = (const float*)d_in[2];
  float* outp = (float*)d_out;
  unsigned short* ws = (unsigned short*)d_ws;

  ea_pack<<<40, 256, 0, stream>>>(Mk, Mv, ws);
  ea_main<<<1024, 256, 0, stream>>>(x, ws, ws + MVP_OFF, outp);
}

// Round 5
// 116.449 us; speedup vs baseline: 1.2160x; 1.0408x over previous
//
#include <hip/hip_runtime.h>

typedef float  f32x4  __attribute__((ext_vector_type(4)));
typedef short  short8 __attribute__((ext_vector_type(8)));
typedef __bf16 bf16x8 __attribute__((ext_vector_type(8)));

#define DEV static __device__ __forceinline__

DEV f32x4 mfma16(short8 a, short8 b, f32x4 c) {
  return __builtin_amdgcn_mfma_f32_16x16x32_bf16(
      __builtin_bit_cast(bf16x8, a), __builtin_bit_cast(bf16x8, b), c, 0, 0, 0);
}

// split f32 into bf16 hi (truncated) + bf16 lo (RNE of residual): hi+lo ~ f to ~2^-15 rel
DEV void splitf(float f, unsigned short& hi, unsigned short& lo) {
  unsigned u = __builtin_bit_cast(unsigned, f);
  hi = (unsigned short)(u >> 16);
  float hf = __builtin_bit_cast(float, u & 0xFFFF0000u);
  float r = f - hf;
  unsigned v = __builtin_bit_cast(unsigned, r);
  lo = (unsigned short)((v + 0x7FFFu + ((v >> 16) & 1u)) >> 16);
}

#define DDIM 640
#define KCH  20            // 640 / 32 k-chunks for GEMM1
#define MKP_ELEMS (KCH*2*4*64*8)   // 81920 ushorts = 163840 B
#define MVP_OFF   MKP_ELEMS

// Pack Mk (fragment order for GEMM1 B) and Mv^T (fragment order for GEMM2 B) as bf16 hi/lo.
// MkP layout: [c(20)][plane(2)][g(4)][lane(64)][j(8)]  ushort
//   holds Mk[m=16g+(l&15)][d=32c+8*(l>>4)+j]
// MvP layout: [n(40)][c(2)][plane(2)][lane(64)][j(8)]  ushort
//   holds Mv[m=32c+8*(l>>4)+j][d=16n+(l&15)]
__global__ void ea_pack(const float* __restrict__ Mk, const float* __restrict__ Mv,
                        unsigned short* __restrict__ ws) {
  int tid = blockIdx.x * 256 + threadIdx.x;
  unsigned short* MkP = ws;
  unsigned short* MvP = ws + MVP_OFF;
  if (tid < 5120) {                       // 20*4*64 slots
    int c = tid >> 8;
    int g = (tid >> 6) & 3;
    int l = tid & 63;
    int t = l & 15, q = l >> 4;
    const float* src = Mk + (16*g + t) * DDIM + 32*c + 8*q;
    unsigned short* dh = MkP + (((c*2 + 0)*4 + g)*64 + l)*8;
    unsigned short* dl = MkP + (((c*2 + 1)*4 + g)*64 + l)*8;
#pragma unroll
    for (int j = 0; j < 8; ++j) splitf(src[j], dh[j], dl[j]);
  } else if (tid < 10240) {               // 40*2*64 slots
    int s = tid - 5120;
    int n = s >> 7;
    int c = (s >> 6) & 1;
    int l = s & 63;
    int t = l & 15, q = l >> 4;
    const float* src = Mv + (32*c + 8*q) * DDIM + 16*n + t;
    unsigned short* dh = MvP + (((n*2 + c)*2 + 0)*64 + l)*8;
    unsigned short* dl = MvP + (((n*2 + c)*2 + 1)*64 + l)*8;
#pragma unroll
    for (int j = 0; j < 8; ++j) splitf(src[j*DDIM], dh[j], dl[j]);
  }
}

// Per-wave, 32 rows/wave (2 row-groups): B-fragments (Mk, Mv) are shared across
// both row-groups -> fragment L2 traffic per row halves vs 16 rows/wave.
// No __syncthreads. x prefetch distance-2 over 3 slots (static indices);
// Mk fragments double-buffered 1 iter ahead; Mv in named A/B buffers.
__global__ __launch_bounds__(256, 2) void ea_main(const float* __restrict__ x,
                                                  const unsigned short* __restrict__ MkP,
                                                  const unsigned short* __restrict__ MvP,
                                                  float* __restrict__ out) {
  __shared__ __align__(16) unsigned short Wh[4][32][64];
  __shared__ __align__(16) unsigned short Wl[4][32][64];
  const int tid = threadIdx.x;
  const int w = tid >> 6;
  const int l = tid & 63;
  const int t = l & 15;
  const int q = l >> 4;
  const long row0 = (long)blockIdx.x * 128 + 32*w;   // this wave's first row

  // ---------------- GEMM1: scores for 32 rows ----------------
  const float* xp0 = x + (row0 + t) * DDIM + 8*q;        // row-group 0
  const float* xp1 = xp0 + 16 * DDIM;                    // row-group 1
  f32x4 acc[2][4];
#pragma unroll
  for (int rg = 0; rg < 2; ++rg)
#pragma unroll
    for (int g = 0; g < 4; ++g) acc[rg][g] = (f32x4){0.f, 0.f, 0.f, 0.f};

  // x prefetch: 3 slots, distance 2 (slot (c+2)%3 != c%3, never collides)
  f32x4 xb[3][2][2];
#pragma unroll
  for (int c = 0; c < 2; ++c) {
    xb[c][0][0] = *(const f32x4*)(xp0 + 32*c);
    xb[c][0][1] = *(const f32x4*)(xp0 + 32*c + 4);
    xb[c][1][0] = *(const f32x4*)(xp1 + 32*c);
    xb[c][1][1] = *(const f32x4*)(xp1 + 32*c + 4);
  }
  // Mk fragment dbuf: slot c&1, prefetched 1 iter ahead
  short8 bh[2][4], bl[2][4];
#pragma unroll
  for (int g = 0; g < 4; ++g) {
    bh[0][g] = *(const short8*)(MkP +        (g*64 + l)*8);
    bl[0][g] = *(const short8*)(MkP + 2048 + (g*64 + l)*8);
  }

#pragma unroll
  for (int c = 0; c < KCH; ++c) {
    // prefetch next iteration's Mk fragments (slot (c+1)&1)
    if (c + 1 < KCH) {
      const unsigned short* mkn = MkP + (c + 1) * 4096;
#pragma unroll
      for (int g = 0; g < 4; ++g) {
        bh[(c+1)&1][g] = *(const short8*)(mkn +        (g*64 + l)*8);
        bl[(c+1)&1][g] = *(const short8*)(mkn + 2048 + (g*64 + l)*8);
      }
    }
    // split x chunk c (consumes slot c%3)
    union { short8 s; unsigned short u[8]; } ah[2], al[2];
#pragma unroll
    for (int rg = 0; rg < 2; ++rg)
#pragma unroll
      for (int i = 0; i < 4; ++i) {
        splitf(xb[c%3][rg][0][i], ah[rg].u[i],     al[rg].u[i]);
        splitf(xb[c%3][rg][1][i], ah[rg].u[4 + i], al[rg].u[4 + i]);
      }
    // prefetch x chunk c+2 into slot (c+2)%3
    if (c + 2 < KCH) {
      xb[(c+2)%3][0][0] = *(const f32x4*)(xp0 + 32*(c+2));
      xb[(c+2)%3][0][1] = *(const f32x4*)(xp0 + 32*(c+2) + 4);
      xb[(c+2)%3][1][0] = *(const f32x4*)(xp1 + 32*(c+2));
      xb[(c+2)%3][1][1] = *(const f32x4*)(xp1 + 32*(c+2) + 4);
    }
    // 24 MFMAs: two independent accumulator chains (rg 0/1) share B-frags
#pragma unroll
    for (int g = 0; g < 4; ++g) {
      acc[0][g] = mfma16(ah[0].s, bh[c&1][g], acc[0][g]);
      acc[1][g] = mfma16(ah[1].s, bh[c&1][g], acc[1][g]);
      acc[0][g] = mfma16(al[0].s, bh[c&1][g], acc[0][g]);
      acc[1][g] = mfma16(al[1].s, bh[c&1][g], acc[1][g]);
      acc[0][g] = mfma16(ah[0].s, bl[c&1][g], acc[0][g]);
      acc[1][g] = mfma16(ah[1].s, bl[c&1][g], acc[1][g]);
    }
  }

  // ---------------- softmax (in-register, per row-group) ----------------
  // lane holds S[row = 16rg + 4q+j][m = 16g+t]
  float rmax[2][4], rsum[2][4];
#pragma unroll
  for (int rg = 0; rg < 2; ++rg) {
#pragma unroll
    for (int j = 0; j < 4; ++j)
      rmax[rg][j] = fmaxf(fmaxf(acc[rg][0][j], acc[rg][1][j]),
                          fmaxf(acc[rg][2][j], acc[rg][3][j]));
#pragma unroll
    for (int mk = 1; mk <= 8; mk <<= 1)
#pragma unroll
      for (int j = 0; j < 4; ++j)
        rmax[rg][j] = fmaxf(rmax[rg][j], __shfl_xor(rmax[rg][j], mk, 64));
#pragma unroll
    for (int g = 0; g < 4; ++g)
#pragma unroll
      for (int j = 0; j < 4; ++j)
        acc[rg][g][j] = exp2f((acc[rg][g][j] - rmax[rg][j]) * 1.44269504f);
#pragma unroll
    for (int j = 0; j < 4; ++j)
      rsum[rg][j] = (acc[rg][0][j] + acc[rg][1][j]) + (acc[rg][2][j] + acc[rg][3][j]);
#pragma unroll
    for (int mk = 1; mk <= 8; mk <<= 1)
#pragma unroll
      for (int j = 0; j < 4; ++j)
        rsum[rg][j] += __shfl_xor(rsum[rg][j], mk, 64);
#pragma unroll
    for (int j = 0; j < 4; ++j) rsum[rg][j] = 1.0f / rsum[rg][j];
  }

  // W -> private LDS slab, XOR swizzle (proven 0-conflict)
#pragma unroll
  for (int rg = 0; rg < 2; ++rg)
#pragma unroll
    for (int g = 0; g < 4; ++g)
#pragma unroll
      for (int j = 0; j < 4; ++j) {
        float wt = acc[rg][g][j] * rsum[rg][j];
        unsigned short hi, lo;
        splitf(wt, hi, lo);
        int row = 16*rg + 4*q + j;
        int ms  = (16*g + t) ^ ((row & 7) << 3);
        Wh[w][row][ms] = hi;
        Wl[w][row][ms] = lo;
      }
  // same-wave cross-lane LDS handoff: wait for all ds_writes to land
  asm volatile("s_waitcnt lgkmcnt(0)" ::: "memory");
  __builtin_amdgcn_sched_barrier(0);

  // hoisted GEMM2 A-fragments: A[row=16rg+t][k=32c+8q+j]  (loop-invariant over n)
  short8 aH[2][2], aL[2][2];
#pragma unroll
  for (int rg = 0; rg < 2; ++rg)
#pragma unroll
    for (int c = 0; c < 2; ++c) {
      const int ms = (32*c + 8*q) ^ ((t & 7) << 3);
      aH[rg][c] = *(const short8*)&Wh[w][16*rg + t][ms];
      aL[rg][c] = *(const short8*)&Wl[w][16*rg + t][ms];
    }

  // ---------------- GEMM2: out = W @ Mv, paired n with named A/B buffers ----------------
  short8 vhA[2], vlA[2], vhB[2], vlB[2];
#pragma unroll
  for (int c = 0; c < 2; ++c) {
    vhA[c] = *(const short8*)(MvP + ((c*2 + 0)*64 + l)*8);
    vlA[c] = *(const short8*)(MvP + ((c*2 + 1)*64 + l)*8);
  }
  float* op0 = out + (row0 + 4*q) * DDIM + t;
  float* op1 = op0 + 16 * DDIM;

#pragma unroll
  for (int np = 0; np < 20; ++np) {
    const int n0 = 2*np, n1 = 2*np + 1;
    // prefetch B for n1
    {
      const unsigned short* mvp = MvP + n1 * 2048;
#pragma unroll
      for (int c = 0; c < 2; ++c) {
        vhB[c] = *(const short8*)(mvp + ((c*2 + 0)*64 + l)*8);
        vlB[c] = *(const short8*)(mvp + ((c*2 + 1)*64 + l)*8);
      }
    }
    // compute n0 with A
    {
      f32x4 o0 = (f32x4){0.f,0.f,0.f,0.f}, o1 = (f32x4){0.f,0.f,0.f,0.f};
#pragma unroll
      for (int c = 0; c < 2; ++c) {
        o0 = mfma16(aH[0][c], vhA[c], o0);
        o1 = mfma16(aH[1][c], vhA[c], o1);
        o0 = mfma16(aL[0][c], vhA[c], o0);
        o1 = mfma16(aL[1][c], vhA[c], o1);
        o0 = mfma16(aH[0][c], vlA[c], o0);
        o1 = mfma16(aH[1][c], vlA[c], o1);
      }
#pragma unroll
      for (int j = 0; j < 4; ++j) {
        op0[16*n0 + j*DDIM] = o0[j];
        op1[16*n0 + j*DDIM] = o1[j];
      }
    }
    // prefetch A for n0+2
    if (np < 19) {
      const unsigned short* mvp = MvP + (n0 + 2) * 2048;
#pragma unroll
      for (int c = 0; c < 2; ++c) {
        vhA[c] = *(const short8*)(mvp + ((c*2 + 0)*64 + l)*8);
        vlA[c] = *(const short8*)(mvp + ((c*2 + 1)*64 + l)*8);
      }
    }
    // compute n1 with B
    {
      f32x4 o0 = (f32x4){0.f,0.f,0.f,0.f}, o1 = (f32x4){0.f,0.f,0.f,0.f};
#pragma unroll
      for (int c = 0; c < 2; ++c) {
        o0 = mfma16(aH[0][c], vhB[c], o0);
        o1 = mfma16(aH[1][c], vhB[c], o1);
        o0 = mfma16(aL[0][c], vhB[c], o0);
        o1 = mfma16(aL[1][c], vhB[c], o1);
        o0 = mfma16(aH[0][c], vlB[c], o0);
        o1 = mfma16(aH[1][c], vlB[c], o1);
      }
#pragma unroll
      for (int j = 0; j < 4; ++j) {
        op0[16*n1 + j*DDIM] = o0[j];
        op1[16*n1 + j*DDIM] = o1[j];
      }
    }
  }
}

extern "C" void kernel_launch(void* const* d_in, const int* in_sizes, int n_in,
                              void* d_out, int out_size, void* d_ws, size_t ws_size,
                              hipStream_t stream) {
  const float* x  = (const float*)d_in[0];
  const float* Mk = (const float*)d_in[1];
  const float* Mv = (const float*)d_in[2];
  float* outp = (float*)d_out;
  unsigned short* ws = (unsigned short*)d_ws;

  ea_pack<<<40, 256, 0, stream>>>(Mk, Mv, ws);
  ea_main<<<512, 256, 0, stream>>>(x, ws, ws + MVP_OFF, outp);
}

// Round 6
// 88.473 us; speedup vs baseline: 1.6005x; 1.3162x over previous
//
#include <hip/hip_runtime.h>

typedef float  f32x4  __attribute__((ext_vector_type(4)));
typedef short  short8 __attribute__((ext_vector_type(8)));
typedef __bf16 bf16x8 __attribute__((ext_vector_type(8)));

#define DEV static __device__ __forceinline__

DEV f32x4 mfma16(short8 a, short8 b, f32x4 c) {
  return __builtin_amdgcn_mfma_f32_16x16x32_bf16(
      __builtin_bit_cast(bf16x8, a), __builtin_bit_cast(bf16x8, b), c, 0, 0, 0);
}

// split f32 into bf16 hi (truncated) + bf16 lo (RNE of residual): hi+lo ~ f to ~2^-15 rel
DEV void splitf(float f, unsigned short& hi, unsigned short& lo) {
  unsigned u = __builtin_bit_cast(unsigned, f);
  hi = (unsigned short)(u >> 16);
  float hf = __builtin_bit_cast(float, u & 0xFFFF0000u);
  float r = f - hf;
  unsigned v = __builtin_bit_cast(unsigned, r);
  lo = (unsigned short)((v + 0x7FFFu + ((v >> 16) & 1u)) >> 16);
}

#define DDIM 640
#define KCH  20            // 640 / 32 k-chunks for GEMM1
#define MKP_ELEMS (KCH*2*4*64*8)   // 81920 ushorts = 163840 B
#define MVP_OFF   MKP_ELEMS

// Pack Mk (fragment order for GEMM1 B) and Mv^T (fragment order for GEMM2 B) as bf16 hi/lo.
// MkP layout: [c(20)][plane(2)][g(4)][lane(64)][j(8)]  ushort
//   holds Mk[m=16g+(l&15)][d=32c+8*(l>>4)+j]
// MvP layout: [n(40)][c(2)][plane(2)][lane(64)][j(8)]  ushort
//   holds Mv[m=32c+8*(l>>4)+j][d=16n+(l&15)]
__global__ void ea_pack(const float* __restrict__ Mk, const float* __restrict__ Mv,
                        unsigned short* __restrict__ ws) {
  int tid = blockIdx.x * 256 + threadIdx.x;
  unsigned short* MkP = ws;
  unsigned short* MvP = ws + MVP_OFF;
  if (tid < 5120) {                       // 20*4*64 slots
    int c = tid >> 8;
    int g = (tid >> 6) & 3;
    int l = tid & 63;
    int t = l & 15, q = l >> 4;
    const float* src = Mk + (16*g + t) * DDIM + 32*c + 8*q;
    unsigned short* dh = MkP + (((c*2 + 0)*4 + g)*64 + l)*8;
    unsigned short* dl = MkP + (((c*2 + 1)*4 + g)*64 + l)*8;
#pragma unroll
    for (int j = 0; j < 8; ++j) splitf(src[j], dh[j], dl[j]);
  } else if (tid < 10240) {               // 40*2*64 slots
    int s = tid - 5120;
    int n = s >> 7;
    int c = (s >> 6) & 1;
    int l = s & 63;
    int t = l & 15, q = l >> 4;
    const float* src = Mv + (32*c + 8*q) * DDIM + 16*n + t;
    unsigned short* dh = MvP + (((n*2 + c)*2 + 0)*64 + l)*8;
    unsigned short* dl = MvP + (((n*2 + c)*2 + 1)*64 + l)*8;
#pragma unroll
    for (int j = 0; j < 8; ++j) splitf(src[j*DDIM], dh[j], dl[j]);
  }
}

// ---- GEMM1 helper macros: ALL buffers are NAMED scalars (no runtime-indexed
// arrays -> nothing can go to scratch). x pipeline: 4 named chunk-pairs,
// each reloaded right after its consumption (prefetch distance = 4 chunks).
#define LOADX(X0, X1, c) { X0 = *(const f32x4*)(xp + 32*(c)); \
                           X1 = *(const f32x4*)(xp + 32*(c) + 4); }

#define LOADF(c) { const unsigned short* mkc_ = MkP + (c)*4096 + l*8;        \
  fh0 = *(const short8*)(mkc_);        fh1 = *(const short8*)(mkc_ + 512);   \
  fh2 = *(const short8*)(mkc_ + 1024); fh3 = *(const short8*)(mkc_ + 1536);  \
  fl0 = *(const short8*)(mkc_ + 2048); fl1 = *(const short8*)(mkc_ + 2560);  \
  fl2 = *(const short8*)(mkc_ + 3072); fl3 = *(const short8*)(mkc_ + 3584); }

#define SPLITX(X0, X1)                                                       \
  splitf(X0[0], ah.u[0], al.u[0]); splitf(X0[1], ah.u[1], al.u[1]);          \
  splitf(X0[2], ah.u[2], al.u[2]); splitf(X0[3], ah.u[3], al.u[3]);          \
  splitf(X1[0], ah.u[4], al.u[4]); splitf(X1[1], ah.u[5], al.u[5]);          \
  splitf(X1[2], ah.u[6], al.u[6]); splitf(X1[3], ah.u[7], al.u[7]);

#define MFMAS()                                                              \
  acc[0] = mfma16(ah.s, fh0, acc[0]); acc[1] = mfma16(ah.s, fh1, acc[1]);    \
  acc[2] = mfma16(ah.s, fh2, acc[2]); acc[3] = mfma16(ah.s, fh3, acc[3]);    \
  acc[0] = mfma16(al.s, fh0, acc[0]); acc[1] = mfma16(al.s, fh1, acc[1]);    \
  acc[2] = mfma16(al.s, fh2, acc[2]); acc[3] = mfma16(al.s, fh3, acc[3]);    \
  acc[0] = mfma16(ah.s, fl0, acc[0]); acc[1] = mfma16(ah.s, fl1, acc[1]);    \
  acc[2] = mfma16(ah.s, fl2, acc[2]); acc[3] = mfma16(ah.s, fl3, acc[3]);

// One wave per block (64 threads), 16 rows/wave, grid 4096 -> 16 blocks/CU.
// Fully independent waves, no barriers; GEMM1 -> in-register softmax ->
// private 4KB LDS slab (XOR swizzle) -> GEMM2 over 40 n -> nontemporal stores.
__global__ __launch_bounds__(64, 4) void ea_main(const float* __restrict__ x,
                                                 const unsigned short* __restrict__ MkP,
                                                 const unsigned short* __restrict__ MvP,
                                                 float* __restrict__ out) {
  __shared__ __align__(16) unsigned short Wh[16][64];
  __shared__ __align__(16) unsigned short Wl[16][64];
  const int l = threadIdx.x;          // 0..63
  const int t = l & 15;
  const int q = l >> 4;
  const long row0 = (long)blockIdx.x * 16;

  // ---------------- GEMM1: scores ----------------
  const float* xp = x + (row0 + t) * DDIM + 8*q;
  f32x4 acc[4];
#pragma unroll
  for (int g = 0; g < 4; ++g) acc[g] = (f32x4){0.f, 0.f, 0.f, 0.f};

  f32x4 x00,x01,x10,x11,x20,x21,x30,x31;
  short8 fh0,fh1,fh2,fh3, fl0,fl1,fl2,fl3;
  union { short8 s; unsigned short u[8]; } ah, al;

  LOADX(x00,x01, 0) LOADX(x10,x11, 1) LOADX(x20,x21, 2) LOADX(x30,x31, 3)

#pragma unroll
  for (int cc = 0; cc < KCH; cc += 4) {
    const bool pf = (cc + 4 < KCH);
    LOADF(cc)     SPLITX(x00, x01) if (pf) { LOADX(x00,x01, cc+4) } MFMAS()
    LOADF(cc+1)   SPLITX(x10, x11) if (pf) { LOADX(x10,x11, cc+5) } MFMAS()
    LOADF(cc+2)   SPLITX(x20, x21) if (pf) { LOADX(x20,x21, cc+6) } MFMAS()
    LOADF(cc+3)   SPLITX(x30, x31) if (pf) { LOADX(x30,x31, cc+7) } MFMAS()
  }

  // ---------------- softmax (in-register) ----------------
  // lane holds S[row = 4q+j][m = 16g+t]
  float rmax[4], rsum[4];
#pragma unroll
  for (int j = 0; j < 4; ++j)
    rmax[j] = fmaxf(fmaxf(acc[0][j], acc[1][j]), fmaxf(acc[2][j], acc[3][j]));
#pragma unroll
  for (int mk = 1; mk <= 8; mk <<= 1) {
#pragma unroll
    for (int j = 0; j < 4; ++j)
      rmax[j] = fmaxf(rmax[j], __shfl_xor(rmax[j], mk, 64));
  }
#pragma unroll
  for (int g = 0; g < 4; ++g)
#pragma unroll
    for (int j = 0; j < 4; ++j)
      acc[g][j] = exp2f((acc[g][j] - rmax[j]) * 1.44269504f);
#pragma unroll
  for (int j = 0; j < 4; ++j)
    rsum[j] = (acc[0][j] + acc[1][j]) + (acc[2][j] + acc[3][j]);
#pragma unroll
  for (int mk = 1; mk <= 8; mk <<= 1) {
#pragma unroll
    for (int j = 0; j < 4; ++j)
      rsum[j] += __shfl_xor(rsum[j], mk, 64);
  }
#pragma unroll
  for (int j = 0; j < 4; ++j) rsum[j] = 1.0f / rsum[j];

  // W -> private LDS slab, XOR swizzle (proven 0-conflict)
#pragma unroll
  for (int g = 0; g < 4; ++g)
#pragma unroll
    for (int j = 0; j < 4; ++j) {
      float wt = acc[g][j] * rsum[j];
      unsigned short hi, lo;
      splitf(wt, hi, lo);
      int row = 4*q + j;
      int ms  = (16*g + t) ^ ((row & 7) << 3);
      Wh[row][ms] = hi;
      Wl[row][ms] = lo;
    }
  // same-wave cross-lane LDS handoff: wait for all ds_writes to land
  asm volatile("s_waitcnt lgkmcnt(0)" ::: "memory");
  __builtin_amdgcn_sched_barrier(0);

  // hoisted GEMM2 A-fragments: A[row=t][k=32c+8q+j]  (loop-invariant over n)
  short8 aH0, aH1, aL0, aL1;
  {
    const int sw  = (t & 7) << 3;
    const int ms0 = (8*q) ^ sw;
    const int ms1 = (32 + 8*q) ^ sw;
    aH0 = *(const short8*)&Wh[t][ms0];
    aH1 = *(const short8*)&Wh[t][ms1];
    aL0 = *(const short8*)&Wl[t][ms0];
    aL1 = *(const short8*)&Wl[t][ms1];
  }

  // ---------------- GEMM2: out = W @ Mv, named A/B Mv buffers ----------------
  short8 vAh0, vAh1, vAl0, vAl1, vBh0, vBh1, vBl0, vBl1;
  {
    const unsigned short* mvp = MvP + l*8;     // n = 0
    vAh0 = *(const short8*)(mvp);        vAl0 = *(const short8*)(mvp + 512);
    vAh1 = *(const short8*)(mvp + 1024); vAl1 = *(const short8*)(mvp + 1536);
  }
  float* opb = out + (row0 + 4*q) * DDIM + t;

#pragma unroll 2
  for (int n = 0; n < 40; n += 2) {
    {   // prefetch B <- n+1
      const unsigned short* mvp = MvP + (n + 1) * 2048 + l*8;
      vBh0 = *(const short8*)(mvp);        vBl0 = *(const short8*)(mvp + 512);
      vBh1 = *(const short8*)(mvp + 1024); vBl1 = *(const short8*)(mvp + 1536);
    }
    {   // compute n with A
      f32x4 o = (f32x4){0.f,0.f,0.f,0.f};
      o = mfma16(aH0, vAh0, o); o = mfma16(aL0, vAh0, o); o = mfma16(aH0, vAl0, o);
      o = mfma16(aH1, vAh1, o); o = mfma16(aL1, vAh1, o); o = mfma16(aH1, vAl1, o);
      float* op = opb + 16*n;
#pragma unroll
      for (int j = 0; j < 4; ++j) __builtin_nontemporal_store(o[j], op + j*DDIM);
    }
    if (n + 2 < 40) {   // prefetch A <- n+2
      const unsigned short* mvp = MvP + (n + 2) * 2048 + l*8;
      vAh0 = *(const short8*)(mvp);        vAl0 = *(const short8*)(mvp + 512);
      vAh1 = *(const short8*)(mvp + 1024); vAl1 = *(const short8*)(mvp + 1536);
    }
    {   // compute n+1 with B
      f32x4 o = (f32x4){0.f,0.f,0.f,0.f};
      o = mfma16(aH0, vBh0, o); o = mfma16(aL0, vBh0, o); o = mfma16(aH0, vBl0, o);
      o = mfma16(aH1, vBh1, o); o = mfma16(aL1, vBh1, o); o = mfma16(aH1, vBl1, o);
      float* op = opb + 16*(n + 1);
#pragma unroll
      for (int j = 0; j < 4; ++j) __builtin_nontemporal_store(o[j], op + j*DDIM);
    }
  }
}

extern "C" void kernel_launch(void* const* d_in, const int* in_sizes, int n_in,
                              void* d_out, int out_size, void* d_ws, size_t ws_size,
                              hipStream_t stream) {
  const float* x  = (const float*)d_in[0];
  const float* Mk = (const float*)d_in[1];
  const float* Mv = (const float*)d_in[2];
  float* outp = (float*)d_out;
  unsigned short* ws = (unsigned short*)d_ws;

  ea_pack<<<40, 256, 0, stream>>>(Mk, Mv, ws);
  ea_main<<<4096, 64, 0, stream>>>(x, ws, ws + MVP_OFF, outp);
}